// Round 2
// baseline (99.099 us; speedup 1.0000x reference)
//
#include <hip/hip_runtime.h>

// Word2vec SGNS loss: sum over B*(K+1)=344064 pairs of softplus(-dot64(u_row,v_row)).
// fp32 embeddings, 1e6 x 64 (256 B rows). ~179 MB random gather -> memory-bound.
// Single fused kernel: grid-stride gather + block partials + ticket-atomic final
// reduce in the last-finishing block (agent-scope atomics for cross-XCD safety).

constexpr int Bn = 16384;
constexpr int Kn = 20;
constexpr int Dn = 64;
constexpr int NPAIRS = Bn * (Kn + 1);   // 344064

#define BDIM 256
#define NBLOCKS 2048
#define NGROUPS ((NBLOCKS * BDIM) >> 4)   // 32768 16-lane groups

__device__ __forceinline__ void pair_idx(
    int p, const int* __restrict__ pu, const int* __restrict__ pv,
    const int* __restrict__ nu, const int* __restrict__ nv, int& iu, int& iv)
{
    if (p < Bn) { iu = pu[p];      iv = pv[p]; }
    else        { iu = nu[p - Bn]; iv = nv[p - Bn]; }
}

__device__ __forceinline__ float softplus_neg(float s) {
    // -log_sigmoid(s) = softplus(-s), stable
    float y = -s;
    return fmaxf(y, 0.f) + log1pf(expf(-fabsf(y)));
}

__device__ __forceinline__ float red16(float s) {
    s += __shfl_xor(s, 1);
    s += __shfl_xor(s, 2);
    s += __shfl_xor(s, 4);
    s += __shfl_xor(s, 8);
    return s;
}

__global__ __launch_bounds__(BDIM) void w2v_fused(
    const int* __restrict__ pos_u, const int* __restrict__ pos_v,
    const int* __restrict__ neg_u, const int* __restrict__ neg_v,
    const float* __restrict__ u_emb, const float* __restrict__ v_emb,
    float* __restrict__ partials, unsigned int* __restrict__ counter,
    float* __restrict__ out)
{
    const int lane16 = threadIdx.x & 15;
    const int group  = (blockIdx.x * BDIM + threadIdx.x) >> 4;
    const int doff   = lane16 << 2;

    float acc = 0.f;
    int p = group;
    // unroll-by-2: 4 outstanding float4 row-loads per group
    for (; p + NGROUPS < NPAIRS; p += 2 * NGROUPS) {
        int iu0, iv0, iu1, iv1;
        pair_idx(p,           pos_u, pos_v, neg_u, neg_v, iu0, iv0);
        pair_idx(p + NGROUPS, pos_u, pos_v, neg_u, neg_v, iu1, iv1);

        const float4 a0 = *reinterpret_cast<const float4*>(u_emb + (size_t)iu0 * Dn + doff);
        const float4 b0 = *reinterpret_cast<const float4*>(v_emb + (size_t)iv0 * Dn + doff);
        const float4 a1 = *reinterpret_cast<const float4*>(u_emb + (size_t)iu1 * Dn + doff);
        const float4 b1 = *reinterpret_cast<const float4*>(v_emb + (size_t)iv1 * Dn + doff);

        float s0 = a0.x*b0.x + a0.y*b0.y + a0.z*b0.z + a0.w*b0.w;
        float s1 = a1.x*b1.x + a1.y*b1.y + a1.z*b1.z + a1.w*b1.w;
        s0 = red16(s0);
        s1 = red16(s1);
        if (lane16 == 0) acc += softplus_neg(s0) + softplus_neg(s1);
    }
    if (p < NPAIRS) {
        int iu, iv;
        pair_idx(p, pos_u, pos_v, neg_u, neg_v, iu, iv);
        const float4 a = *reinterpret_cast<const float4*>(u_emb + (size_t)iu * Dn + doff);
        const float4 b = *reinterpret_cast<const float4*>(v_emb + (size_t)iv * Dn + doff);
        float s = a.x*b.x + a.y*b.y + a.z*b.z + a.w*b.w;
        s = red16(s);
        if (lane16 == 0) acc += softplus_neg(s);
    }

    // block reduction: acc lives at lanes 0 mod 16
    acc += __shfl_xor(acc, 16);
    acc += __shfl_xor(acc, 32);
    __shared__ float red[BDIM / 64];
    if ((threadIdx.x & 63) == 0) red[threadIdx.x >> 6] = acc;
    __syncthreads();

    __shared__ bool is_last;
    if (threadIdx.x == 0) {
        float bsum = red[0] + red[1] + red[2] + red[3];
        // agent-scope store so other XCDs' L2 sees it
        __hip_atomic_store(&partials[blockIdx.x], bsum, __ATOMIC_RELAXED,
                           __HIP_MEMORY_SCOPE_AGENT);
        unsigned t = __hip_atomic_fetch_add(counter, 1u, __ATOMIC_ACQ_REL,
                                            __HIP_MEMORY_SCOPE_AGENT);
        is_last = (t == NBLOCKS - 1);
    }
    __syncthreads();

    if (is_last) {
        float s = 0.f;
        for (int i = threadIdx.x; i < NBLOCKS; i += BDIM)
            s += __hip_atomic_load(&partials[i], __ATOMIC_RELAXED,
                                   __HIP_MEMORY_SCOPE_AGENT);
        s += __shfl_xor(s, 1);
        s += __shfl_xor(s, 2);
        s += __shfl_xor(s, 4);
        s += __shfl_xor(s, 8);
        s += __shfl_xor(s, 16);
        s += __shfl_xor(s, 32);
        __shared__ float red2[BDIM / 64];
        if ((threadIdx.x & 63) == 0) red2[threadIdx.x >> 6] = s;
        __syncthreads();
        if (threadIdx.x == 0) out[0] = red2[0] + red2[1] + red2[2] + red2[3];
    }
}

extern "C" void kernel_launch(void* const* d_in, const int* in_sizes, int n_in,
                              void* d_out, int out_size, void* d_ws, size_t ws_size,
                              hipStream_t stream) {
    const int*   pos_u = (const int*)d_in[0];
    const int*   pos_v = (const int*)d_in[1];
    const int*   neg_u = (const int*)d_in[2];
    const int*   neg_v = (const int*)d_in[3];
    const float* u_emb = (const float*)d_in[4];
    const float* v_emb = (const float*)d_in[5];
    float* out = (float*)d_out;

    unsigned int* counter  = (unsigned int*)d_ws;              // 4 B
    float*        partials = (float*)((char*)d_ws + 256);      // NBLOCKS floats

    // counter must start at 0 every call (ws is poisoned once, not restored)
    hipMemsetAsync(d_ws, 0, sizeof(unsigned int), stream);

    w2v_fused<<<NBLOCKS, BDIM, 0, stream>>>(pos_u, pos_v, neg_u, neg_v,
                                            u_emb, v_emb, partials, counter, out);
}

// Round 3
// 38.371 us; speedup vs baseline: 2.5827x; 2.5827x over previous
//
#include <hip/hip_runtime.h>

// Word2vec SGNS loss: sum over B*(K+1)=344064 pairs of softplus(-dot64(u_row,v_row)).
// fp32 embeddings, 1e6 x 64 (256 B rows). Random gather, latency-bound:
// ~149 MB unique rows, ~88 MB from HBM (L3 retains rest across replays).
// Two kernels: grid-stride gather w/ 4-pair unroll -> block partials; 1-block reduce.
// (Round-2 lesson: single-address agent-scope ACQ_REL atomics serialized ~130us — avoid.)

constexpr int Bn = 16384;
constexpr int Kn = 20;
constexpr int Dn = 64;
constexpr int NPAIRS = Bn * (Kn + 1);   // 344064

#define BDIM 256
#define NBLOCKS 2048
#define NGROUPS ((NBLOCKS * BDIM) >> 4)   // 32768 16-lane groups

__device__ __forceinline__ void pair_idx(
    int p, const int* __restrict__ pu, const int* __restrict__ pv,
    const int* __restrict__ nu, const int* __restrict__ nv, int& iu, int& iv)
{
    if (p < Bn) { iu = pu[p];      iv = pv[p]; }
    else        { iu = nu[p - Bn]; iv = nv[p - Bn]; }
}

__device__ __forceinline__ float softplus_neg(float s) {
    // -log_sigmoid(s) = softplus(-s), stable
    float y = -s;
    return fmaxf(y, 0.f) + log1pf(expf(-fabsf(y)));
}

__device__ __forceinline__ float red16(float s) {
    s += __shfl_xor(s, 1);
    s += __shfl_xor(s, 2);
    s += __shfl_xor(s, 4);
    s += __shfl_xor(s, 8);
    return s;
}

__global__ __launch_bounds__(BDIM) void w2v_partial(
    const int* __restrict__ pos_u, const int* __restrict__ pos_v,
    const int* __restrict__ neg_u, const int* __restrict__ neg_v,
    const float* __restrict__ u_emb, const float* __restrict__ v_emb,
    float* __restrict__ partials)
{
    const int lane16 = threadIdx.x & 15;
    const int group  = (blockIdx.x * BDIM + threadIdx.x) >> 4;
    const int doff   = lane16 << 2;

    float acc = 0.f;
    int p = group;

    // 4-pair unroll: 8 outstanding float4 row-gathers per group (statically indexed)
    for (; p + 3 * NGROUPS < NPAIRS; p += 4 * NGROUPS) {
        int iu0, iv0, iu1, iv1, iu2, iv2, iu3, iv3;
        pair_idx(p,               pos_u, pos_v, neg_u, neg_v, iu0, iv0);
        pair_idx(p +     NGROUPS, pos_u, pos_v, neg_u, neg_v, iu1, iv1);
        pair_idx(p + 2 * NGROUPS, pos_u, pos_v, neg_u, neg_v, iu2, iv2);
        pair_idx(p + 3 * NGROUPS, pos_u, pos_v, neg_u, neg_v, iu3, iv3);

        const float4 a0 = *reinterpret_cast<const float4*>(u_emb + (size_t)iu0 * Dn + doff);
        const float4 b0 = *reinterpret_cast<const float4*>(v_emb + (size_t)iv0 * Dn + doff);
        const float4 a1 = *reinterpret_cast<const float4*>(u_emb + (size_t)iu1 * Dn + doff);
        const float4 b1 = *reinterpret_cast<const float4*>(v_emb + (size_t)iv1 * Dn + doff);
        const float4 a2 = *reinterpret_cast<const float4*>(u_emb + (size_t)iu2 * Dn + doff);
        const float4 b2 = *reinterpret_cast<const float4*>(v_emb + (size_t)iv2 * Dn + doff);
        const float4 a3 = *reinterpret_cast<const float4*>(u_emb + (size_t)iu3 * Dn + doff);
        const float4 b3 = *reinterpret_cast<const float4*>(v_emb + (size_t)iv3 * Dn + doff);

        float s0 = a0.x*b0.x + a0.y*b0.y + a0.z*b0.z + a0.w*b0.w;
        float s1 = a1.x*b1.x + a1.y*b1.y + a1.z*b1.z + a1.w*b1.w;
        float s2 = a2.x*b2.x + a2.y*b2.y + a2.z*b2.z + a2.w*b2.w;
        float s3 = a3.x*b3.x + a3.y*b3.y + a3.z*b3.z + a3.w*b3.w;
        s0 = red16(s0); s1 = red16(s1); s2 = red16(s2); s3 = red16(s3);
        if (lane16 == 0)
            acc += (softplus_neg(s0) + softplus_neg(s1)) +
                   (softplus_neg(s2) + softplus_neg(s3));
    }
    for (; p < NPAIRS; p += NGROUPS) {
        int iu, iv;
        pair_idx(p, pos_u, pos_v, neg_u, neg_v, iu, iv);
        const float4 a = *reinterpret_cast<const float4*>(u_emb + (size_t)iu * Dn + doff);
        const float4 b = *reinterpret_cast<const float4*>(v_emb + (size_t)iv * Dn + doff);
        float s = a.x*b.x + a.y*b.y + a.z*b.z + a.w*b.w;
        s = red16(s);
        if (lane16 == 0) acc += softplus_neg(s);
    }

    // block reduction: acc lives at lanes 0 mod 16
    acc += __shfl_xor(acc, 16);
    acc += __shfl_xor(acc, 32);
    __shared__ float red[BDIM / 64];
    if ((threadIdx.x & 63) == 0) red[threadIdx.x >> 6] = acc;
    __syncthreads();
    if (threadIdx.x == 0)
        partials[blockIdx.x] = red[0] + red[1] + red[2] + red[3];
}

__global__ __launch_bounds__(BDIM) void w2v_reduce(
    const float* __restrict__ partials, float* __restrict__ out)
{
    float s = 0.f;
    for (int i = threadIdx.x; i < NBLOCKS; i += BDIM) s += partials[i];
    s += __shfl_xor(s, 1);
    s += __shfl_xor(s, 2);
    s += __shfl_xor(s, 4);
    s += __shfl_xor(s, 8);
    s += __shfl_xor(s, 16);
    s += __shfl_xor(s, 32);
    __shared__ float red[BDIM / 64];
    if ((threadIdx.x & 63) == 0) red[threadIdx.x >> 6] = s;
    __syncthreads();
    if (threadIdx.x == 0) out[0] = red[0] + red[1] + red[2] + red[3];
}

extern "C" void kernel_launch(void* const* d_in, const int* in_sizes, int n_in,
                              void* d_out, int out_size, void* d_ws, size_t ws_size,
                              hipStream_t stream) {
    const int*   pos_u = (const int*)d_in[0];
    const int*   pos_v = (const int*)d_in[1];
    const int*   neg_u = (const int*)d_in[2];
    const int*   neg_v = (const int*)d_in[3];
    const float* u_emb = (const float*)d_in[4];
    const float* v_emb = (const float*)d_in[5];
    float* out = (float*)d_out;
    float* partials = (float*)d_ws;   // NBLOCKS floats = 8 KB

    w2v_partial<<<NBLOCKS, BDIM, 0, stream>>>(pos_u, pos_v, neg_u, neg_v,
                                              u_emb, v_emb, partials);
    w2v_reduce<<<1, BDIM, 0, stream>>>(partials, out);
}